// Round 1
// 138.635 us; speedup vs baseline: 1.0087x; 1.0087x over previous
//
#include <hip/hip_runtime.h>
#include <hip/hip_bf16.h>
#include <math.h>

// ProxyGML: B=1024, DIM=512, C=1000, N=8
#define PB   1024
#define PDIM 512
#define PC   1000
#define PN   8
#define PCN  8000
#define PTOPK 400
#define NONPOS_K 392
#define NBIN 1024
#define CANDMAX 1024

typedef __bf16 bf16x8 __attribute__((ext_vector_type(8)));
typedef __bf16 bf16x4 __attribute__((ext_vector_type(4)));
typedef float  f32x4  __attribute__((ext_vector_type(4)));

__device__ static inline void async_load16(const __bf16* g, __bf16* l) {
    __builtin_amdgcn_global_load_lds(
        (const __attribute__((address_space(1))) void*)g,
        (__attribute__((address_space(3))) void*)l,
        16, 0, 0);
}

// ----------------------------------------------------------------- pre ----
// b<512: x->bf16. 512..767: P column-ssq partials. 768+: zero esum/diag and
// ccls pad rows (classes 1000..1023).
__global__ __launch_bounds__(256) void k_pre(const float* __restrict__ x,
                                             const float* __restrict__ P,
                                             __bf16* __restrict__ xb,
                                             float* __restrict__ ssqp,
                                             float* __restrict__ esd,
                                             float* __restrict__ padf,
                                             float* __restrict__ acc) {
    int b = blockIdx.x, tid = threadIdx.x;
    if (b == 0 && tid < 8) acc[tid] = 0.f;
    if (b < 512) {
        int i = b * 256 + tid;
        float4 v = ((const float4*)x)[i];
        bf16x4 o;
        o[0] = (__bf16)v.x; o[1] = (__bf16)v.y; o[2] = (__bf16)v.z; o[3] = (__bf16)v.w;
        ((bf16x4*)xb)[i] = o;
    } else if (b < 768) {
        int idx = b - 512;              // 0..255
        int slice = idx & 7, jb = idx >> 3;
        int j = jb * 256 + tid;
        if (j < PCN) {
            const float* p = P + (size_t)(slice * 64) * PCN + j;
            float ss = 0.f;
#pragma unroll 8
            for (int r = 0; r < 64; ++r) {
                float v = p[(size_t)r * PCN];
                ss = fmaf(v, v, ss);
            }
            ssqp[slice * PCN + j] = ss;
        }
    } else {
        int i = (b - 768) * 256 + tid;  // 0..22271
        if (i < 16000) esd[i] = 0.f;
        else if (i < 16000 + 6144) padf[i - 16000] = 0.f;  // 24x512 bf16 pad
    }
}

// ---------------- P (512x8000) -> Pt bf16 (8000x512) + fused ccls ---------
__global__ __launch_bounds__(256) void k_tpose(const float* __restrict__ P,
                                               const float* __restrict__ ssqp,
                                               __bf16* __restrict__ Pt,
                                               __bf16* __restrict__ ccls) {
    __shared__ float t[64][65];
    __shared__ float sinv[64];
    int tid = threadIdx.x;
    int tx = tid & 63, ty = tid >> 6;
    int j0 = blockIdx.x * 64, d0 = blockIdx.y * 64;
    if (tid < 64) {
        float sq = 0.f;
#pragma unroll
        for (int p2 = 0; p2 < 8; ++p2) sq += ssqp[p2 * PCN + j0 + tid];
        sinv[tid] = 1.0f / fmaxf(sqrtf(sq), 1e-12f);
    }
#pragma unroll
    for (int r = 0; r < 16; ++r) {
        int d = d0 + ty * 16 + r;
        t[ty * 16 + r][tx] = P[(size_t)d * PCN + j0 + tx];
    }
    __syncthreads();
    float cs0 = 0.f, cs1 = 0.f;
#pragma unroll
    for (int r = 0; r < 16; ++r) {
        int jl = ty * 16 + r;
        float val = t[tx][jl] * sinv[jl];
        Pt[(size_t)(j0 + jl) * PDIM + d0 + tx] = (__bf16)val;
        if (r < 8) cs0 += val; else cs1 += val;
    }
    int c0 = (j0 >> 3) + ty * 2;           // 16 j's = 2 whole classes
    ccls[(size_t)c0 * PDIM + d0 + tx] = (__bf16)cs0;
    ccls[(size_t)(c0 + 1) * PDIM + d0 + tx] = (__bf16)cs1;
}

// ------------- 256^2-tile counted-vmcnt GEMM (two GEMMs by block id) ------
// bid<128 : sim[m][j]  = xb(1024x512) . Pt(8000x512)^T   (NT form)
// bid>=128: clog[j][c] = Pt(8000x512) . ccls(1024x512)^T (NT form)
// BM=BN=256, BK=64, 8 waves (2Mx4N), per-wave 128x64 out, 128 KiB LDS dbuf.
// LDS tiles are [256 rows][8 slots of 16B]; physical slot = logical ^ (row&7)
// (conflict-free ds_read_b128: 8 consecutive rows cover all 32 banks).
// global_load_lds writes linearly; the XOR is applied to the GLOBAL source
// k-offset (rule 21: linear dest + inverse-swizzled source + swizzled read).
// Schedule per K-tile: lgkm(0); barrier; STAGE(kt+1); vmcnt(8); barrier;
// 2x { 12 ds_read_b128 ; setprio(1) ; 32 MFMA ; setprio(0) }.
// vmcnt(8) = next tile's 8 loads stay in flight (never drain in main loop).
__global__ __launch_bounds__(512, 2) void k_gemms2(const __bf16* __restrict__ xb,
                                                   const __bf16* __restrict__ Pt,
                                                   const __bf16* __restrict__ ccls,
                                                   __bf16* __restrict__ simb,
                                                   float* __restrict__ esum,
                                                   float* __restrict__ diag) {
    __shared__ __align__(16) __bf16 As[2][256 * 64];   // 64 KiB
    __shared__ __align__(16) __bf16 Bs[2][256 * 64];   // 64 KiB

    int tid = threadIdx.x;
    int w = tid >> 6, lane = tid & 63;
    int wr = w >> 2, wc = w & 3;           // 2M x 4N waves
    int quad = lane >> 4, l15 = lane & 15;

    int bid = blockIdx.x;
    bool is_sim = bid < 128;
    int M0, N0, Amax, Bmax;
    const __bf16 *Ab, *Bb;
    if (is_sim) {
        int mt = bid >> 5, nt = bid & 31;  // 4 x 32 tiles
        M0 = mt * 256; N0 = nt * 256;
        Ab = xb; Bb = Pt; Amax = PB - 1; Bmax = PCN - 1;
    } else {
        int b2 = bid - 128;
        int mt = b2 >> 2, nt = b2 & 3;     // 32 x 4 tiles
        M0 = mt * 256; N0 = nt * 256;
        Ab = Pt; Bb = ccls; Amax = PCN - 1; Bmax = 1023;
    }

    f32x4 acc[8][4] = {};

#define STAGE(kt_) {                                                         \
    int k0_ = (kt_) * 64, bb_ = (kt_) & 1;                                   \
    _Pragma("unroll")                                                        \
    for (int p_ = 0; p_ < 4; ++p_) {                                         \
        int idx_ = p_ * 512 + tid;                                           \
        int row_ = idx_ >> 3, sp_ = idx_ & 7;                                \
        int gk_ = ((sp_ ^ (row_ & 7)) << 3) + k0_;                           \
        int ga_ = M0 + row_; if (ga_ > Amax) ga_ = Amax;                     \
        async_load16(Ab + (size_t)ga_ * PDIM + gk_, &As[bb_][idx_ * 8]);     \
        int gb_ = N0 + row_; if (gb_ > Bmax) gb_ = Bmax;                     \
        async_load16(Bb + (size_t)gb_ * PDIM + gk_, &Bs[bb_][idx_ * 8]);     \
    } }

    STAGE(0)
    for (int kt = 0; kt < 8; ++kt) {
        int cur = kt & 1;
        asm volatile("s_waitcnt lgkmcnt(0)" ::: "memory");
        __builtin_amdgcn_s_barrier();            // all reads of buf^1 done
        if (kt < 7) {
            STAGE(kt + 1)                        // -> buf^1 (nobody reads it now)
            asm volatile("s_waitcnt vmcnt(8)" ::: "memory");  // kt's 8 retired
        } else {
            asm volatile("s_waitcnt vmcnt(0)" ::: "memory");  // tail drain
        }
        __builtin_amdgcn_s_barrier();            // buf[cur] fully staged

#pragma unroll
        for (int ks = 0; ks < 2; ++ks) {
            bf16x8 af[8], bfr[4];
#pragma unroll
            for (int mi = 0; mi < 8; ++mi) {
                int row = wr * 128 + mi * 16 + l15;
                af[mi] = *(const bf16x8*)&As[cur][(row << 6) +
                         ((((ks << 2) + quad) ^ (row & 7)) << 3)];
            }
#pragma unroll
            for (int nj = 0; nj < 4; ++nj) {
                int row = wc * 64 + nj * 16 + l15;
                bfr[nj] = *(const bf16x8*)&Bs[cur][(row << 6) +
                          ((((ks << 2) + quad) ^ (row & 7)) << 3)];
            }
            __builtin_amdgcn_s_setprio(1);
#pragma unroll
            for (int mi = 0; mi < 8; ++mi)
#pragma unroll
                for (int nj = 0; nj < 4; ++nj)
                    acc[mi][nj] = __builtin_amdgcn_mfma_f32_16x16x32_bf16(
                        af[mi], bfr[nj], acc[mi][nj], 0, 0, 0);
            __builtin_amdgcn_s_setprio(0);
        }
    }
#undef STAGE

    if (is_sim) {
        // sim store: rows M0+.., cols N0+.. over CN (guard 8000)
#pragma unroll
        for (int mi = 0; mi < 8; ++mi) {
            int r0 = M0 + wr * 128 + mi * 16 + quad * 4;
#pragma unroll
            for (int nj = 0; nj < 4; ++nj) {
                int cc = N0 + wc * 64 + nj * 16 + l15;
                if (cc < PCN) {
#pragma unroll
                    for (int r = 0; r < 4; ++r)
                        simb[(size_t)(r0 + r) * PCN + cc] = (__bf16)acc[mi][nj][r];
                }
            }
        }
    } else {
        // clog -> esum/diag (rows N-dim = classes, guard 1000; m-rows over CN)
#pragma unroll
        for (int mi = 0; mi < 8; ++mi) {
            int r0 = M0 + wr * 128 + mi * 16 + quad * 4;
            float psum[4] = {0.f, 0.f, 0.f, 0.f};
#pragma unroll
            for (int nj = 0; nj < 4; ++nj) {
                int cc = N0 + wc * 64 + nj * 16 + l15;
                bool cvalid = (cc < PC);
#pragma unroll
                for (int r = 0; r < 4; ++r) {
                    float v = acc[mi][nj][r];
                    psum[r] += cvalid ? expf(v) : 0.f;
                    int rr = r0 + r;
                    if (cvalid && rr < PCN && cc == (rr >> 3)) diag[rr] = v;
                }
            }
#pragma unroll
            for (int off = 1; off < 16; off <<= 1)
#pragma unroll
                for (int r = 0; r < 4; ++r)
                    psum[r] += __shfl_xor(psum[r], off, 64);
            if (l15 == 0) {
#pragma unroll
                for (int r = 0; r < 4; ++r) {
                    int rr = r0 + r;
                    if (rr < PCN) atomicAdd(&esum[rr], psum[r]);
                }
            }
        }
    }
}

// ------------------------------------------------------------- row loss ---
// Register-resident bf16 row; 1024-bin histogram select for tau; ties
// resolved by index order via parallel class-order prefix scan.
__global__ __launch_bounds__(256) void k_rowloss(const __bf16* __restrict__ sim,
                                                 const int* __restrict__ target,
                                                 float* __restrict__ acc) {
    __shared__ unsigned hist[NBIN];
    __shared__ float redf[8];
    __shared__ unsigned wtot[4];
    __shared__ float cand[CANDMAX];
    __shared__ unsigned candn;
    __shared__ int s_bin, s_A;
    __shared__ float s_tau;
    __shared__ int s_gt, s_eq;
    __shared__ float s_et;

    int b = blockIdx.x, tid = threadIdx.x;
    int lane = tid & 63, wv = tid >> 6;
    const bf16x8* row8 = (const bf16x8*)(sim + (size_t)b * PCN);
    int targ = target[b];

#pragma unroll
    for (int k = 0; k < 4; ++k) hist[tid + 256 * k] = 0u;
    if (tid == 0) candn = 0u;

    float pv[4][8];
    float lmn = INFINITY, lmx = -INFINITY;
#pragma unroll
    for (int k = 0; k < 4; ++k) {
        int c = tid + 256 * k;
        if (c < PC) {
            bf16x8 vv = row8[c];
#pragma unroll
            for (int n = 0; n < 8; ++n) pv[k][n] = (float)vv[n];
            if (c != targ) {
#pragma unroll
                for (int n = 0; n < 8; ++n) {
                    lmn = fminf(lmn, pv[k][n]);
                    lmx = fmaxf(lmx, pv[k][n]);
                }
            }
        } else {
#pragma unroll
            for (int n = 0; n < 8; ++n) pv[k][n] = 0.f;
        }
    }
    for (int off = 32; off; off >>= 1) {
        lmn = fminf(lmn, __shfl_down(lmn, off, 64));
        lmx = fmaxf(lmx, __shfl_down(lmx, off, 64));
    }
    if (lane == 0) { redf[wv] = lmn; redf[4 + wv] = lmx; }
    __syncthreads();
    float lo = fminf(fminf(redf[0], redf[1]), fminf(redf[2], redf[3]));
    float hi = fmaxf(fmaxf(redf[4], redf[5]), fmaxf(redf[6], redf[7]));
    float range = hi - lo;
    float scale = (range > 0.f) ? (float)NBIN / range : 0.f;

#pragma unroll
    for (int k = 0; k < 4; ++k) {
        int c = tid + 256 * k;
        if (c < PC && c != targ) {
#pragma unroll
            for (int n = 0; n < 8; ++n) {
                int bin = (int)((pv[k][n] - lo) * scale);
                bin = bin < 0 ? 0 : (bin > NBIN - 1 ? NBIN - 1 : bin);
                atomicAdd(&hist[bin], 1u);
            }
        }
    }
    __syncthreads();

    // suffix scan over 1024 bins
    int b0 = tid * 4;
    unsigned h0 = hist[b0], h1 = hist[b0 + 1], h2 = hist[b0 + 2], h3 = hist[b0 + 3];
    unsigned l3 = h3, l2 = h2 + l3, l1 = h1 + l2, l0 = h0 + l1;
    unsigned T = l0;
#pragma unroll
    for (int step = 1; step < 64; step <<= 1) {
        unsigned u = __shfl_down(T, step, 64);
        if (lane + step < 64) T += u;
    }
    if (lane == 0) wtot[wv] = T;
    __syncthreads();
    unsigned tail = 0;
#pragma unroll
    for (int w2 = 0; w2 < 4; ++w2) if (w2 > wv) tail += wtot[w2];
    unsigned E = T - l0 + tail;
    {
        unsigned sfx[4] = {l0 + E, l1 + E, l2 + E, l3 + E};
        unsigned nxt[4] = {l1 + E, l2 + E, l3 + E, E};
#pragma unroll
        for (int i = 0; i < 4; ++i)
            if (sfx[i] >= NONPOS_K && nxt[i] < NONPOS_K) {
                s_bin = b0 + i;
                s_A = (int)nxt[i];
            }
    }
    __syncthreads();
    int tbin = s_bin, A = s_A;

    // collect candidates in tau's bin
#pragma unroll
    for (int k = 0; k < 4; ++k) {
        int c = tid + 256 * k;
        if (c < PC && c != targ) {
#pragma unroll
            for (int n = 0; n < 8; ++n) {
                int bin = (int)((pv[k][n] - lo) * scale);
                bin = bin < 0 ? 0 : (bin > NBIN - 1 ? NBIN - 1 : bin);
                if (bin == tbin) {
                    unsigned idx = atomicAdd(&candn, 1u);
                    if (idx < CANDMAX) cand[idx] = pv[k][n];
                }
            }
        }
    }
    __syncthreads();
    int m = (int)candn; if (m > CANDMAX) m = CANDMAX;
    int rank = NONPOS_K - A;
    for (int ci = tid; ci < m; ci += 256) {
        float val = cand[ci];
        int g = 0, e = 0;
        for (int i = 0; i < m; ++i) {
            g += cand[i] > val;
            e += cand[i] == val;
        }
        if (g < rank && rank <= g + e) { s_tau = val; s_gt = g; s_eq = e; }
    }
    __syncthreads();
    float tau = s_tau;
    int cgt = A + s_gt, ceq = s_eq;
    int rem = NONPOS_K - cgt;              // ties to include, by index order
    bool all_eq = (rem >= ceq);

    // parallel tie offsets in class-index order
    int offs[4] = {0, 0, 0, 0};
    if (!all_eq) {
        unsigned chunk_base = 0;
#pragma unroll
        for (int k = 0; k < 4; ++k) {
            int c = tid + 256 * k;
            unsigned tn = 0;
            if (c < PC && c != targ) {
#pragma unroll
                for (int n = 0; n < 8; ++n) tn += (pv[k][n] == tau) ? 1u : 0u;
            }
            unsigned inc = tn;                       // inclusive wave scan
#pragma unroll
            for (int step = 1; step < 64; step <<= 1) {
                unsigned u = __shfl_up(inc, step, 64);
                if (lane >= step) inc += u;
            }
            __syncthreads();
            if (lane == 63) wtot[wv] = inc;
            __syncthreads();
            unsigned base = 0;
#pragma unroll
            for (int w2 = 0; w2 < 4; ++w2) if (w2 < wv) base += wtot[w2];
            offs[k] = (int)(chunk_base + base + inc - tn);
            chunk_base += wtot[0] + wtot[1] + wtot[2] + wtot[3];
        }
    }

    // logits -> exp -> loss
    float psum = 0.f;
#pragma unroll
    for (int k = 0; k < 4; ++k) {
        int c = tid + 256 * k;
        if (c >= PC) continue;
        float lg = 0.f;
        if (c == targ) {
#pragma unroll
            for (int n = 0; n < 8; ++n) lg += pv[k][n];
        } else {
#pragma unroll
            for (int n = 0; n < 8; ++n) {
                float v = pv[k][n];
                bool sel = v > tau;
                if (!sel && v == tau) {
                    if (all_eq) sel = true;
                    else { sel = (offs[k] < rem); offs[k]++; }
                }
                if (sel) lg += v;
            }
        }
        float e = (lg != 0.0f) ? expf(lg) : 0.0f;
        psum += e;
        if (c == targ) s_et = e;
    }
    for (int off = 32; off; off >>= 1) psum += __shfl_down(psum, off, 64);
    if (lane == 0) redf[wv] = psum;
    __syncthreads();
    if (tid == 0) {
        float denom = 1e-8f + redf[0] + redf[1] + redf[2] + redf[3];
        atomicAdd(acc, -logf(s_et / denom + 1e-20f));
    }
}

// --------------------------------------------------------------- final ----
__global__ __launch_bounds__(256) void k_final(const float* __restrict__ esum,
                                               const float* __restrict__ diag,
                                               const float* __restrict__ acc,
                                               float* __restrict__ out) {
    __shared__ float redf[4];
    int tid = threadIdx.x, lane = tid & 63, wv = tid >> 6;
    float s = 0.f;
    for (int j = tid; j < PCN; j += 256)
        s += logf(esum[j]) - diag[j];
    for (int off = 32; off; off >>= 1) s += __shfl_down(s, off, 64);
    if (lane == 0) redf[wv] = s;
    __syncthreads();
    if (tid == 0) {
        float rg = (redf[0] + redf[1] + redf[2] + redf[3]) * (1.0f / PCN);
        float lc = acc[0] * (1.0f / PB);
        out[0] = lc + 0.3f * rg;
        out[1] = lc;
    }
}

// ---------------------------------------------------------------------------
extern "C" void kernel_launch(void* const* d_in, const int* in_sizes, int n_in,
                              void* d_out, int out_size, void* d_ws, size_t ws_size,
                              hipStream_t stream) {
    const float* x       = (const float*)d_in[0];   // (1024, 512)
    const float* proxies = (const float*)d_in[1];   // (512, 8000)
    const int*   target  = (const int*)d_in[2];     // (1024,)
    float* out = (float*)d_out;
    float* ws  = (float*)d_ws;

    // workspace layout (float offsets) — spans verified:
    //   acc    [0,      64)
    //   ssqp   [64,     64064)     8x8000 f32
    //   esum   [64064,  72064)     8000 f32
    //   diag   [72064,  80064)     8000 f32
    //   xb     [80064,  342208)    1024x512 bf16 = 262144 f32
    //   cclsb  [342208, 604352)    1024x512 bf16 = 262144 f32
    //   Pt     [604352, 2652352)   8000x512 bf16 = 2048000 f32
    //   simb   [2652352,6748352)   1024x8000 bf16 = 4096000 f32
    float*  acc   = ws;
    float*  ssqp  = ws + 64;
    float*  esum  = ws + 64064;
    float*  diag  = ws + 72064;
    __bf16* xb    = (__bf16*)(ws + 80064);
    __bf16* cclsb = (__bf16*)(ws + 342208);
    __bf16* Pt    = (__bf16*)(ws + 604352);
    __bf16* simb  = (__bf16*)(ws + 2652352);
    // total 6,748,352 floats = 27.0 MiB

    float* padf = (float*)cclsb + 256000;     // ccls rows 1000..1023 as f32

    k_pre<<<856, 256, 0, stream>>>(x, proxies, xb, ssqp, esum, padf, acc);
    k_tpose<<<dim3(125, 8), 256, 0, stream>>>(proxies, ssqp, Pt, cclsb);

    k_gemms2<<<256, 512, 0, stream>>>(xb, Pt, cclsb, simb, esum, diag);

    k_rowloss<<<PB, 256, 0, stream>>>(simb, target, acc);
    k_final<<<1, 256, 0, stream>>>(esum, diag, acc, out);
}